// Round 14
// baseline (92.424 us; speedup 1.0000x reference)
//
#include <hip/hip_runtime.h>

typedef short bf16x8 __attribute__((ext_vector_type(8)));
typedef float f32x16 __attribute__((ext_vector_type(16)));

#define BIG_F 1e10f
constexpr int B = 16;
constexpr int N = 4096;
constexpr int COLS = 512;           // staged cols per block
constexpr int NCB = N / COLS;       // 8
constexpr int PASSES = 2;           // 256-row passes (2 streams each)
constexpr int SUBROWS = 512;        // rows per block
constexpr int NSUB = N / SUBROWS;   // 8
// per-direction partials: [B][NCB][2 ssets][N]
constexpr size_t PARTSZ = (size_t)B * NCB * 2 * N;   // 4 MB of floats

// truncating bf16 hi/lo split: v ~= hi + lo
__device__ __forceinline__ void split(float v, unsigned& h, unsigned& l) {
    unsigned hb = __float_as_uint(v) & 0xFFFF0000u;
    h = hb >> 16;
    float r = v - __uint_as_float(hb);
    l = __float_as_uint(r) >> 16;
}

__device__ __forceinline__ float min3f(float a, float b, float c) {
    return fminf(fminf(a, b), c);   // fuses to v_min3_f32
}

__device__ __forceinline__ float4 min4(float4 a, float4 b) {
    return make_float4(fminf(a.x, b.x), fminf(a.y, b.y),
                       fminf(a.z, b.z), fminf(a.w, b.w));
}

// VALU-pipe cross-lane min via DPP (no ds-op). Validated exact (R8/R9/R11/R13).
#define DPP_MIN(v, ctrl)                                                      \
    v = fminf(v, __int_as_float(__builtin_amdgcn_update_dpp(                  \
            __float_as_int(v), __float_as_int(v), (ctrl), 0xF, 0xF, false)))

// Fragment styles (identical arithmetic to all passing rounds):
// ROWstyle(point v, s=|v|^2+madd): k = [ah0..2,ah0..2,al0..2, sh,sl,1,1] (a=-2v)
// COLstyle(point v, s=|v|^2+madd): k = [vh0..2,vl0..2,vh0..2,vl0..2, 1,1, sh,sl]
__device__ __forceinline__ void rowstyle(float v0, float v1, float v2,
                                         float madd, uint4& w0, uint4& w1) {
    float s = fmaf(v2, v2, fmaf(v1, v1, v0 * v0)) + madd;
    unsigned h0, l0, h1, l1, h2, l2, sh, sl;
    split(-2.0f * v0, h0, l0);
    split(-2.0f * v1, h1, l1);
    split(-2.0f * v2, h2, l2);
    split(s, sh, sl);
    w0 = make_uint4(h0 | (h1 << 16), h2 | (h0 << 16), h1 | (h2 << 16), l0 | (l1 << 16));
    w1 = make_uint4(l2 | (l0 << 16), l1 | (l2 << 16), sh | (sl << 16), 0x3F803F80u);
}
__device__ __forceinline__ void colstyle(float v0, float v1, float v2,
                                         float madd, uint4& w0, uint4& w1) {
    float s = fmaf(v2, v2, fmaf(v1, v1, v0 * v0)) + madd;
    unsigned h0, l0, h1, l1, h2, l2, sh, sl;
    split(v0, h0, l0);
    split(v1, h1, l1);
    split(v2, h2, l2);
    split(s, sh, sl);
    unsigned u0 = h0 | (h1 << 16), u1 = h2 | (l0 << 16), u2 = l1 | (l2 << 16);
    w0 = make_uint4(u0, u1, u2, u0);
    w1 = make_uint4(u1, u2, 0x3F803F80u, sh | (sl << 16));
}

// R14: symmetric two-direction scheme. dir0: mfma(A=rowstyle(x), B=colstyle(y))
// -> row-mins = mins2 (per-x). dir1: mfma(A=colstyle(y), B=rowstyle(x)) ->
// C'[m][n] has the SAME 16 exact bf16-product terms in the SAME k-slots as
// C[n][m] -> bit-identical P; row-mins = mins1 (per-y). This deletes the
// entire col-min path (vmin16 trees + colbuf rmw + barrier + combine) = ~65%
// of inner-loop VALU. Inner loop: 2 ds_read, 4 MFMA, 32 min3f. Register shape
// strictly leaner than R13's validated (256,3) ILP-2 shape.
__global__ __launch_bounds__(256, 3) void chamfer_mfma(
    const float* __restrict__ x, const float* __restrict__ y,
    const int* __restrict__ mask,
    float* __restrict__ part,      // [2][B][NCB][2][N]: dir0=mins2, dir1=mins1
    float* __restrict__ out)
{
    const int blk  = blockIdx.x;    // 0..2047
    const int dir  = blk & 1;
    const int rest = blk >> 1;
    const int b    = rest >> 6;
    const int cb   = (rest >> 3) & 7;
    const int sub  = rest & 7;
    const int t    = threadIdx.x;

    __shared__ __align__(16) unsigned short Bpack[2][COLS][8];  // 16 KB

    if (blk == 0 && t == 0) out[0] = 0.0f;   // finalize is the next dispatch

    const float* rsrc = dir ? y : x;   // row side (per-lane A fragments)
    const float* csrc = dir ? x : y;   // col side (staged B fragments)
    const int*   mb   = mask + b * N;
    const float* rb3  = rsrc + (size_t)b * 3 * N;
    const float* cb3  = csrc + (size_t)b * 3 * N;

    // ---- stage this block's 512-col slice (2 points/thread) ----
#pragma unroll
    for (int i = 0; i < 2; ++i) {
        int c = t + i * 256;
        int m = cb * COLS + c;
        float v0 = cb3[m], v1 = cb3[N + m], v2 = cb3[2 * N + m];
        float madd = mb[m] ? 0.0f : BIG_F;
        uint4 w0, w1;
        if (dir) rowstyle(v0, v1, v2, madd, w0, w1);
        else     colstyle(v0, v1, v2, madd, w0, w1);
        *(uint4*)&Bpack[0][c][0] = w0;
        *(uint4*)&Bpack[1][c][0] = w1;
    }

    const int w    = t >> 6;    // wave 0..3
    const int L    = t & 63;
    const int half = L >> 5;    // k-half 0/1
    const int lc   = L & 31;

    __syncthreads();

    const unsigned short* Bb = &Bpack[half][lc][0];  // +p*512 shorts = col p*64+lc

    const f32x16 z16 = {0.f,0.f,0.f,0.f,0.f,0.f,0.f,0.f,
                        0.f,0.f,0.f,0.f,0.f,0.f,0.f,0.f};

    auto buildA = [&](int n) -> bf16x8 {
        float v0 = rb3[n], v1 = rb3[N + n], v2 = rb3[2 * N + n];
        float madd = mb[n] ? 0.0f : BIG_F;
        uint4 w0, w1;
        if (dir) colstyle(v0, v1, v2, madd, w0, w1);
        else     rowstyle(v0, v1, v2, madd, w0, w1);
        uint4 wa = half ? w1 : w0;
        return *(bf16x8*)&wa;
    };

    float* pbase = part + (size_t)dir * PARTSZ;

#pragma unroll 1
    for (int pass = 0; pass < PASSES; ++pass) {
        const int rowbase = sub * SUBROWS + pass * 256;
        // two 32-row streams per wave: rows rowbase+w*32 (A), +128 (B)
        bf16x8 afrA = buildA(rowbase + w * 32 + lc);
        bf16x8 afrB = buildA(rowbase + 128 + w * 32 + lc);

        float rmA[16], rmB[16];
#pragma unroll
        for (int r = 0; r < 16; ++r) { rmA[r] = 1e30f; rmB[r] = 1e30f; }

#pragma unroll 1
        for (int p = 0; p < 8; ++p) {          // 8 col-pairs of 32 = 512 cols
            bf16x8 bf0 = *(const bf16x8*)(Bb + p * 512);
            bf16x8 bf1 = *(const bf16x8*)(Bb + p * 512 + 256);
            f32x16 C0a = __builtin_amdgcn_mfma_f32_32x32x16_bf16(afrA, bf0, z16, 0, 0, 0);
            f32x16 C0b = __builtin_amdgcn_mfma_f32_32x32x16_bf16(afrB, bf0, z16, 0, 0, 0);
            f32x16 C1a = __builtin_amdgcn_mfma_f32_32x32x16_bf16(afrA, bf1, z16, 0, 0, 0);
            f32x16 C1b = __builtin_amdgcn_mfma_f32_32x32x16_bf16(afrB, bf1, z16, 0, 0, 0);
            // C[r]: row = base + (r&3)+8*(r>>2)+4*half, col = p*64(+32)+lc
#pragma unroll
            for (int r = 0; r < 16; ++r) {
                rmA[r] = min3f(rmA[r], C0a[r], C1a[r]);
                rmB[r] = min3f(rmB[r], C0b[r], C1b[r]);
            }
        }

        // ---- row-min over each 16-lane group, entirely on the VALU pipe ----
#pragma unroll
        for (int r = 0; r < 16; ++r) {
            DPP_MIN(rmA[r], 0xB1);   DPP_MIN(rmB[r], 0xB1);   // quad xor1
            DPP_MIN(rmA[r], 0x4E);   DPP_MIN(rmB[r], 0x4E);   // quad xor2
            DPP_MIN(rmA[r], 0x124);  DPP_MIN(rmB[r], 0x124);  // row_ror:4
            DPP_MIN(rmA[r], 0x128);  DPP_MIN(rmB[r], 0x128);  // row_ror:8
        }
        if ((lc & 15) == 0) {        // lanes 0,16,32,48: (half, col-subset)
            int sset = lc >> 4;
            float* rpA = pbase + (((size_t)(b * NCB + cb)) * 2 + sset) * N
                       + rowbase + w * 32 + half * 4;
            float* rpB = rpA + 128;
            *(float4*)(rpA +  0) = make_float4(rmA[0],  rmA[1],  rmA[2],  rmA[3]);
            *(float4*)(rpA +  8) = make_float4(rmA[4],  rmA[5],  rmA[6],  rmA[7]);
            *(float4*)(rpA + 16) = make_float4(rmA[8],  rmA[9],  rmA[10], rmA[11]);
            *(float4*)(rpA + 24) = make_float4(rmA[12], rmA[13], rmA[14], rmA[15]);
            *(float4*)(rpB +  0) = make_float4(rmB[0],  rmB[1],  rmB[2],  rmB[3]);
            *(float4*)(rpB +  8) = make_float4(rmB[4],  rmB[5],  rmB[6],  rmB[7]);
            *(float4*)(rpB + 16) = make_float4(rmB[8],  rmB[9],  rmB[10], rmB[11]);
            *(float4*)(rpB + 24) = make_float4(rmB[12], rmB[13], rmB[14], rmB[15]);
        }
    }
}

__global__ __launch_bounds__(256) void finalize_kernel(
    const int* __restrict__ mask,
    const float* __restrict__ part,
    float* __restrict__ out)
{
    const int b = blockIdx.x & 15;
    const int q = blockIdx.x >> 4;   // quarter 0..3
    const int t = threadIdx.x;
    const int* mrow = mask + b * N;

    int cnt = 0;
    for (int i = t; i < N / 4; i += 256) {
        int4 mk = ((const int4*)mrow)[i];
        cnt += mk.x + mk.y + mk.z + mk.w;
    }

    const int p0 = q * 1024 + t * 4;
    const float* d0 = part + (size_t)b * NCB * 2 * N + p0;            // mins2
    const float* d1 = part + PARTSZ + (size_t)b * NCB * 2 * N + p0;   // mins1

    float4 rn = *(const float4*)d0;
    float4 mn = *(const float4*)d1;
#pragma unroll 8
    for (int pb = 1; pb < NCB * 2; ++pb) {
        rn = min4(rn, *(const float4*)(d0 + (size_t)pb * N));
        mn = min4(mn, *(const float4*)(d1 + (size_t)pb * N));
    }
    int4 mk = *(const int4*)(mrow + p0);
    float s = (mk.x ? (mn.x + rn.x) : 0.f) + (mk.y ? (mn.y + rn.y) : 0.f)
            + (mk.z ? (mn.z + rn.z) : 0.f) + (mk.w ? (mn.w + rn.w) : 0.f);

    for (int off = 32; off > 0; off >>= 1) {
        s   += __shfl_down(s, off);
        cnt += __shfl_down(cnt, off);
    }
    __shared__ float rs[4];
    __shared__ int   rc[4];
    const int wv = t >> 6;
    if ((t & 63) == 0) { rs[wv] = s; rc[wv] = cnt; }
    __syncthreads();
    if (t == 0) {
        float S = rs[0] + rs[1] + rs[2] + rs[3];
        float C = (float)(rc[0] + rc[1] + rc[2] + rc[3]);
        atomicAdd(out, (S / C) * (1.0f / 16.0f));
    }
}

extern "C" void kernel_launch(void* const* d_in, const int* in_sizes, int n_in,
                              void* d_out, int out_size, void* d_ws, size_t ws_size,
                              hipStream_t stream) {
    const float* x    = (const float*)d_in[0];
    const float* y    = (const float*)d_in[1];
    const int*   mask = (const int*)d_in[2];

    float* part = (float*)d_ws;   // 2 * PARTSZ floats = 8 MB

    chamfer_mfma<<<dim3(2 * B * NCB * NSUB), 256, 0, stream>>>(
        x, y, mask, part, (float*)d_out);
    finalize_kernel<<<dim3(64), 256, 0, stream>>>(
        mask, part, (float*)d_out);
}